// Round 18
// baseline (227.366 us; speedup 1.0000x reference)
//
#include <hip/hip_runtime.h>
#include <hip/hip_cooperative_groups.h>

namespace cg = cooperative_groups;

#define NA 100000
#define NE 300000
#define STEPS 4
#define NTILES (NE / 16)        // 18750 (exact)
#define ATILES (NA / 16)        // 6250  (exact)

typedef _Float16 f16;
typedef _Float16 half8 __attribute__((ext_vector_type(8)));
using f32x4 = __attribute__((ext_vector_type(4))) float;

// ---------------------------------------------------------------------------
// msg over NBR-SORTED edges: h-gather is quasi-sequential (16 slots span ~5
// h-rows); the random side is a fire-and-forget 64B store to msg[dpos].
// ---------------------------------------------------------------------------
__device__ __forceinline__ void msg_body(
    const f16* __restrict__ h, const f16* __restrict__ bondq,
    const int* __restrict__ srcn, const int* __restrict__ dpos,
    const f16* __restrict__ Wbt, f16* __restrict__ msgb,
    int wid, int nw, int col, int kg)
{
    half8 w0[17], w1[17];
#pragma unroll
    for (int t = 0; t < 17; ++t) {
        w0[t] = *reinterpret_cast<const half8*>(Wbt + (t * 32 + col) * 32 + kg * 8);
        w1[t] = *reinterpret_cast<const half8*>(Wbt + (t * 32 + 16 + col) * 32 + kg * 8);
    }
    int tile = wid;
    int dp = 0;
    half8 hf{}, cA{}, cB{};
    if (tile < NTILES) {
        int slot = tile * 16 + col;
        int sn = srcn[slot];
        dp = dpos[slot];
        cA = *reinterpret_cast<const half8*>(bondq + (size_t)slot * 16);
        cB = *reinterpret_cast<const half8*>(bondq + (size_t)slot * 16 + 8);
        hf = *reinterpret_cast<const half8*>(h + (size_t)sn * 32 + kg * 8);
    }
    while (tile < NTILES) {
        int tile2 = tile + nw;
        int dp2 = 0;
        half8 hf2{}, cA2{}, cB2{};
        if (tile2 < NTILES) {
            int slot2 = tile2 * 16 + col;
            int sn2 = srcn[slot2];
            dp2 = dpos[slot2];
            cA2 = *reinterpret_cast<const half8*>(bondq + (size_t)slot2 * 16);
            cB2 = *reinterpret_cast<const half8*>(bondq + (size_t)slot2 * 16 + 8);
            hf2 = *reinterpret_cast<const half8*>(h + (size_t)sn2 * 32 + kg * 8);
        }
        f32x4 acc0 = {0.f, 0.f, 0.f, 0.f};
        f32x4 acc1 = {0.f, 0.f, 0.f, 0.f};
#pragma unroll
        for (int t = 0; t < 16; ++t) {
            f16 ch = (t < 8) ? cA[t] : cB[t - 8];
            half8 a = hf * ch;               // v_pk_mul_f16 x4
            acc0 = __builtin_amdgcn_mfma_f32_16x16x32_f16(w0[t], a, acc0, 0, 0, 0);
            acc1 = __builtin_amdgcn_mfma_f32_16x16x32_f16(w1[t], a, acc1, 0, 0, 0);
        }
        acc0 = __builtin_amdgcn_mfma_f32_16x16x32_f16(w0[16], hf, acc0, 0, 0, 0);
        acc1 = __builtin_amdgcn_mfma_f32_16x16x32_f16(w1[16], hf, acc1, 0, 0, 0);

        half8 so;   // i = kg*8 .. kg*8+7 (contiguous via Wbt row permute)
        so[0]=(f16)acc0[0]; so[1]=(f16)acc0[1]; so[2]=(f16)acc0[2]; so[3]=(f16)acc0[3];
        so[4]=(f16)acc1[0]; so[5]=(f16)acc1[1]; so[6]=(f16)acc1[2]; so[7]=(f16)acc1[3];
        *reinterpret_cast<half8*>(msgb + (size_t)dp * 32 + kg * 8) = so;

        tile = tile2; dp = dp2; hf = hf2; cA = cA2; cB = cB2;
    }
}

__device__ __forceinline__ void gru_body(
    const f16* __restrict__ msgb, const int* __restrict__ start,
    const int* __restrict__ cnt, f16* __restrict__ h,
    const f16* __restrict__ Wihb, const f16* __restrict__ Whhb,
    const float* __restrict__ bih, const float* __restrict__ bhh,
    float* __restrict__ hout, int wf, int wid, int nw, int col, int kg)
{
    half8 wi[6], wh[6];
#pragma unroll
    for (int t = 0; t < 6; ++t) {
        wi[t] = *reinterpret_cast<const half8*>(Wihb + (size_t)(t * 16 + col) * 32 + kg * 8);
        wh[t] = *reinterpret_cast<const half8*>(Whhb + (size_t)(t * 16 + col) * 32 + kg * 8);
    }
    float br0  = bih[col]      + bhh[col];
    float bz0  = bih[32 + col] + bhh[32 + col];
    float bin0 = bih[64 + col];
    float bhn0 = bhh[64 + col];
    float br1  = bih[16 + col] + bhh[16 + col];
    float bz1  = bih[48 + col] + bhh[48 + col];
    float bin1 = bih[80 + col];
    float bhn1 = bhh[80 + col];

    for (int tile = wid; tile < ATILES; tile += nw) {
        int base = tile * 16;
        int a0   = base + col;
        int st = start[a0], en = st + cnt[a0];
        half8 hfrag = *reinterpret_cast<const half8*>(h + (size_t)a0 * 32 + kg * 8);

        float xs[8] = {0.f, 0.f, 0.f, 0.f, 0.f, 0.f, 0.f, 0.f};
        int p = st;
        while (p < en) {
            int n = en - p;
            half8 m0, m1, m2, m3;
            m0 = *reinterpret_cast<const half8*>(msgb + (size_t)p * 32 + kg * 8);
            if (n > 1) m1 = *reinterpret_cast<const half8*>(msgb + (size_t)(p + 1) * 32 + kg * 8);
            if (n > 2) m2 = *reinterpret_cast<const half8*>(msgb + (size_t)(p + 2) * 32 + kg * 8);
            if (n > 3) m3 = *reinterpret_cast<const half8*>(msgb + (size_t)(p + 3) * 32 + kg * 8);
#pragma unroll
            for (int j = 0; j < 8; ++j) xs[j] += (float)m0[j];
            if (n > 1) {
#pragma unroll
                for (int j = 0; j < 8; ++j) xs[j] += (float)m1[j];
            }
            if (n > 2) {
#pragma unroll
                for (int j = 0; j < 8; ++j) xs[j] += (float)m2[j];
            }
            if (n > 3) {
#pragma unroll
                for (int j = 0; j < 8; ++j) xs[j] += (float)m3[j];
            }
            p += 4;
        }
        half8 xfrag;
#pragma unroll
        for (int j = 0; j < 8; ++j) xfrag[j] = (f16)xs[j];

        f32x4 gi[6], gh[6];
#pragma unroll
        for (int t = 0; t < 6; ++t) {
            f32x4 z = {0.f, 0.f, 0.f, 0.f};
            gi[t] = __builtin_amdgcn_mfma_f32_16x16x32_f16(xfrag, wi[t], z, 0, 0, 0);
            gh[t] = __builtin_amdgcn_mfma_f32_16x16x32_f16(hfrag, wh[t], z, 0, 0, 0);
        }

#pragma unroll
        for (int hh = 0; hh < 2; ++hh) {
            float br  = hh ? br1  : br0;
            float bz  = hh ? bz1  : bz0;
            float bin = hh ? bin1 : bin0;
            float bhn = hh ? bhn1 : bhn0;
            int i = hh * 16 + col;
#pragma unroll
            for (int reg = 0; reg < 4; ++reg) {
                int a = base + kg * 4 + reg;
                float r = 1.f / (1.f + __expf(-(gi[hh][reg] + gh[hh][reg] + br)));
                float z = 1.f / (1.f + __expf(-(gi[2 + hh][reg] + gh[2 + hh][reg] + bz)));
                float n = tanhf(gi[4 + hh][reg] + bin + r * (gh[4 + hh][reg] + bhn));
                float hp = (float)h[(size_t)a * 32 + i];
                float o  = (1.f - z) * n + z * hp;
                if (wf) hout[(size_t)a * 32 + i] = o;
                h[(size_t)a * 32 + i] = (f16)o;
            }
        }
    }
}

// ---------------------------------------------------------------------------
// setup / scatter items
// ---------------------------------------------------------------------------
__device__ __forceinline__ void setup_item(
    int t, const float* __restrict__ atom,
    const float* __restrict__ Wb, const float* __restrict__ bb,
    const float* __restrict__ Wih, const float* __restrict__ Whh,
    f16* __restrict__ hbf, f16* __restrict__ Wbt,
    f16* __restrict__ Wihb, f16* __restrict__ Whhb,
    int* __restrict__ cntd, int* __restrict__ cntn,
    int* __restrict__ total, int* __restrict__ total2)
{
    const int NH8 = NA * 32 / 8;                 // 400000
    if (t < NH8) {
        float4 a = reinterpret_cast<const float4*>(atom)[2 * t];
        float4 b = reinterpret_cast<const float4*>(atom)[2 * t + 1];
        half8 o;
        o[0]=(f16)a.x; o[1]=(f16)a.y; o[2]=(f16)a.z; o[3]=(f16)a.w;
        o[4]=(f16)b.x; o[5]=(f16)b.y; o[6]=(f16)b.z; o[7]=(f16)b.w;
        reinterpret_cast<half8*>(hbf)[t] = o;
        return;
    }
    int u = t - NH8;
    if (u < 2 * NA) {
        if (u < NA) cntd[u] = 0; else cntn[u - NA] = 0;
        if (u == 0) { *total = 0; *total2 = 0; }
        return;
    }
    int v = u - 2 * NA;
    if (v < 17 * 32 * 32) {
        int j = v & 31, i = (v >> 5) & 31, k = v >> 10;
        float val = (k < 16) ? Wb[k * 1024 + i * 32 + j] : bb[i * 32 + j];
        int row = ((i & 4) ? 16 : 0) + ((i >> 3) << 2) + (i & 3);  // i = kg*8.. permute
        Wbt[(k * 32 + row) * 32 + j] = (f16)val;
    } else if (v < 17 * 32 * 32 + 3072) {
        int q = v - 17 * 32 * 32;
        Wihb[q] = (f16)Wih[q];
    } else if (v < 17 * 32 * 32 + 6144) {
        int q = v - 17 * 32 * 32 - 3072;
        Whhb[q] = (f16)Whh[q];
    }
}

__device__ __forceinline__ void scatter_item(
    int e, const float* __restrict__ bond, const int* __restrict__ pair,
    int* __restrict__ nextd, int* __restrict__ nextn,
    int* __restrict__ srcn, int* __restrict__ dpos, f16* __restrict__ bondq)
{
    int2 p = reinterpret_cast<const int2*>(pair)[e];
    int pos  = atomicAdd(&nextd[p.x], 1);   // dst-sorted position (gru layout)
    int slot = atomicAdd(&nextn[p.y], 1);   // nbr-sorted slot (msg order)
    srcn[slot] = p.y;
    dpos[slot] = pos;
    const float4* b4 = reinterpret_cast<const float4*>(bond + (size_t)e * 16);
    float4 b0 = b4[0], b1 = b4[1], b2 = b4[2], b3 = b4[3];
    half8 o0, o1;
    o0[0]=(f16)b0.x; o0[1]=(f16)b0.y; o0[2]=(f16)b0.z; o0[3]=(f16)b0.w;
    o0[4]=(f16)b1.x; o0[5]=(f16)b1.y; o0[6]=(f16)b1.z; o0[7]=(f16)b1.w;
    o1[0]=(f16)b2.x; o1[1]=(f16)b2.y; o1[2]=(f16)b2.z; o1[3]=(f16)b2.w;
    o1[4]=(f16)b3.x; o1[5]=(f16)b3.y; o1[6]=(f16)b3.z; o1[7]=(f16)b3.w;
    half8* dst = reinterpret_cast<half8*>(bondq + (size_t)slot * 16);
    dst[0] = o0; dst[1] = o1;
}

#define SETUP_THREADS (NA * 32 / 8 + 2 * NA + 17 * 32 * 32 + 6144)

// ---------------------------------------------------------------------------
// mega kernel: setup -> hist(x2) -> alloc(x2) -> scatter -> 4x(msg,gru)
// ---------------------------------------------------------------------------
__global__ __launch_bounds__(256, 2) void mega_kernel(
    const float* __restrict__ atom, const float* __restrict__ bond,
    const int* __restrict__ pair,
    const float* __restrict__ Wb, const float* __restrict__ bb,
    const float* __restrict__ Wih, const float* __restrict__ Whh,
    const float* __restrict__ bih, const float* __restrict__ bhh,
    f16* __restrict__ hbf, f16* __restrict__ Wbt,
    f16* __restrict__ Wihb, f16* __restrict__ Whhb,
    int* __restrict__ cntd, int* __restrict__ startd, int* __restrict__ nextd,
    int* __restrict__ cntn, int* __restrict__ startn, int* __restrict__ nextn,
    int* __restrict__ srcn, int* __restrict__ dpos, f16* __restrict__ bondq,
    f16* __restrict__ msgb, int* __restrict__ total, int* __restrict__ total2,
    float* __restrict__ hout)
{
    __shared__ int scan[256];
    __shared__ int sbase;

    cg::grid_group grid = cg::this_grid();
    int gtid = blockIdx.x * 256 + threadIdx.x;
    int gsz  = gridDim.x * 256;

    // phase 0: converts + zeroing + weight prep
    for (int t = gtid; t < SETUP_THREADS; t += gsz)
        setup_item(t, atom, Wb, bb, Wih, Whh, hbf, Wbt, Wihb, Whhb,
                   cntd, cntn, total, total2);
    grid.sync();

    // phase 1: degree histograms (dst and nbr)
    for (int e = gtid; e < NE; e += gsz) {
        int2 p = reinterpret_cast<const int2*>(pair)[e];
        atomicAdd(&cntd[p.x], 1);
        atomicAdd(&cntn[p.y], 1);
    }
    grid.sync();

    // phase 2: segment allocation for both orders (256-chunk scan + atomic base)
    const int NCHUNK = (NA + 255) / 256;
#pragma unroll 1
    for (int pass = 0; pass < 2; ++pass) {
        const int* c  = pass ? cntn   : cntd;
        int* st = pass ? startn : startd;
        int* nx = pass ? nextn  : nextd;
        int* tt = pass ? total2 : total;
        for (int chunk = blockIdx.x; chunk < NCHUNK; chunk += gridDim.x) {
            int g = chunk * 256 + threadIdx.x;
            int v = (g < NA) ? c[g] : 0;
            scan[threadIdx.x] = v;
            __syncthreads();
            for (int off = 1; off < 256; off <<= 1) {
                int u = (threadIdx.x >= off) ? scan[threadIdx.x - off] : 0;
                __syncthreads();
                scan[threadIdx.x] += u;
                __syncthreads();
            }
            if (threadIdx.x == 255) sbase = atomicAdd(tt, scan[255]);
            __syncthreads();
            if (g < NA) {
                int s = sbase + scan[threadIdx.x] - v;
                st[g] = s;
                nx[g] = s;
            }
            __syncthreads();
        }
    }
    grid.sync();

    // phase 3: scatter into nbr-sorted slots (+ dst positions)
    for (int e = gtid; e < NE; e += gsz)
        scatter_item(e, bond, pair, nextd, nextn, srcn, dpos, bondq);
    grid.sync();

    // phase 4: the 4-step loop
    int wave = threadIdx.x >> 6;
    int lane = threadIdx.x & 63;
    int col  = lane & 15;
    int kg   = lane >> 4;
    int wid  = blockIdx.x * 4 + wave;
    int nw   = gridDim.x << 2;

    for (int s = 0; s < STEPS; ++s) {
        msg_body(hbf, bondq, srcn, dpos, Wbt, msgb, wid, nw, col, kg);
        grid.sync();
        gru_body(msgb, startd, cntd, hbf, Wihb, Whhb, bih, bhh, hout,
                 (s == STEPS - 1) ? 1 : 0, wid, nw, col, kg);
        grid.sync();
    }
}

// ---------------------------------------------------------------------------
// fallback path kernels
// ---------------------------------------------------------------------------
__global__ __launch_bounds__(256) void setup_kernel(
    const float* __restrict__ atom,
    const float* __restrict__ Wb, const float* __restrict__ bb,
    const float* __restrict__ Wih, const float* __restrict__ Whh,
    f16* __restrict__ hbf, f16* __restrict__ Wbt,
    f16* __restrict__ Wihb, f16* __restrict__ Whhb,
    int* __restrict__ cntd, int* __restrict__ cntn,
    int* __restrict__ total, int* __restrict__ total2)
{
    int t = blockIdx.x * 256 + threadIdx.x;
    if (t < SETUP_THREADS)
        setup_item(t, atom, Wb, bb, Wih, Whh, hbf, Wbt, Wihb, Whhb,
                   cntd, cntn, total, total2);
}

__global__ __launch_bounds__(256) void hist_kernel(
    const int* __restrict__ pair, int* __restrict__ cntd, int* __restrict__ cntn)
{
    int e = blockIdx.x * 256 + threadIdx.x;
    if (e < NE) {
        int2 p = reinterpret_cast<const int2*>(pair)[e];
        atomicAdd(&cntd[p.x], 1);
        atomicAdd(&cntn[p.y], 1);
    }
}

__global__ __launch_bounds__(1024) void alloc_kernel(
    const int* __restrict__ cnt, int* __restrict__ start,
    int* __restrict__ next, int* __restrict__ total)
{
    __shared__ int tmp[1024];
    __shared__ int base;
    int g = blockIdx.x * 1024 + threadIdx.x;
    int v = (g < NA) ? cnt[g] : 0;
    tmp[threadIdx.x] = v;
    __syncthreads();
    for (int off = 1; off < 1024; off <<= 1) {
        int u = (threadIdx.x >= off) ? tmp[threadIdx.x - off] : 0;
        __syncthreads();
        tmp[threadIdx.x] += u;
        __syncthreads();
    }
    if (threadIdx.x == 1023) base = atomicAdd(total, tmp[1023]);
    __syncthreads();
    if (g < NA) {
        int s = base + tmp[threadIdx.x] - v;
        start[g] = s;
        next[g] = s;
    }
}

__global__ __launch_bounds__(256) void scatter_kernel(
    const float* __restrict__ bond, const int* __restrict__ pair,
    int* __restrict__ nextd, int* __restrict__ nextn,
    int* __restrict__ srcn, int* __restrict__ dpos, f16* __restrict__ bondq)
{
    int e = blockIdx.x * 256 + threadIdx.x;
    if (e < NE) scatter_item(e, bond, pair, nextd, nextn, srcn, dpos, bondq);
}

__global__ __launch_bounds__(256, 2) void msg_kernel(
    const f16* __restrict__ hb, const f16* __restrict__ bondq,
    const int* __restrict__ srcn, const int* __restrict__ dpos,
    const f16* __restrict__ Wbt, f16* __restrict__ msgb)
{
    int wave = threadIdx.x >> 6;
    int lane = threadIdx.x & 63;
    msg_body(hb, bondq, srcn, dpos, Wbt, msgb,
             blockIdx.x * 4 + wave, gridDim.x << 2, lane & 15, lane >> 4);
}

__global__ __launch_bounds__(256) void gru_kernel(
    const f16* __restrict__ msgb, const int* __restrict__ start,
    const int* __restrict__ cnt, f16* __restrict__ hb,
    const f16* __restrict__ Wihb, const f16* __restrict__ Whhb,
    const float* __restrict__ bih, const float* __restrict__ bhh,
    float* __restrict__ hout, int wf)
{
    int wave = threadIdx.x >> 6;
    int lane = threadIdx.x & 63;
    gru_body(msgb, start, cnt, hb, Wihb, Whhb, bih, bhh, hout, wf,
             blockIdx.x * 4 + wave, gridDim.x << 2, lane & 15, lane >> 4);
}

extern "C" void kernel_launch(void* const* d_in, const int* in_sizes, int n_in,
                              void* d_out, int out_size, void* d_ws, size_t ws_size,
                              hipStream_t stream)
{
    const float* atom = (const float*)d_in[0];
    const float* bond = (const float*)d_in[1];
    const int*   pair = (const int*)  d_in[2];
    const float* Wb   = (const float*)d_in[3];
    const float* bb   = (const float*)d_in[4];
    const float* W_ih = (const float*)d_in[5];
    const float* W_hh = (const float*)d_in[6];
    const float* b_ih = (const float*)d_in[7];
    const float* b_hh = (const float*)d_in[8];
    float* out = (float*)d_out;

    char* w = (char*)d_ws;                       // ws >= 256 MB (poison fill shows 262144 KB)
    f16* msg    = (f16*)w;                       // 19,200,000 B
    f16* hbf    = (f16*)(w + 19200000);          //  6,400,000
    f16* bondq  = (f16*)(w + 25600000);          //  9,600,000
    f16* Wbt    = (f16*)(w + 35200000);          //     34,816
    f16* Wihb   = Wbt + 17 * 32 * 32;            //      6,144
    f16* Whhb   = Wihb + 96 * 32;                //      6,144
    int* cntd   = (int*)(w + 35248000);          //    400,000
    int* startd = (int*)(w + 35648000);          //    400,000
    int* nextd  = (int*)(w + 36048000);          //    400,000
    int* cntn   = (int*)(w + 36448000);          //    400,000
    int* startn = (int*)(w + 36848000);          //    400,000
    int* nextn  = (int*)(w + 37248000);          //    400,000
    int* srcn   = (int*)(w + 37648000);          //  1,200,000
    int* dpos   = (int*)(w + 38848000);          //  1,200,000
    int* total  = (int*)(w + 40048000);          //          4
    int* total2 = (int*)(w + 40048008);          //          4

    int bpc = 0;
    hipError_t qe = hipOccupancyMaxActiveBlocksPerMultiprocessor(
        &bpc, (const void*)mega_kernel, 256, 0);
    if (qe == hipSuccess && bpc >= 2) {
        int nblk = bpc * 256;
        if (nblk > 2048) nblk = 2048;
        void* args[24];
        args[0]  = (void*)&atom;  args[1]  = (void*)&bond;  args[2]  = (void*)&pair;
        args[3]  = (void*)&Wb;    args[4]  = (void*)&bb;
        args[5]  = (void*)&W_ih;  args[6]  = (void*)&W_hh;
        args[7]  = (void*)&b_ih;  args[8]  = (void*)&b_hh;
        args[9]  = &hbf;    args[10] = &Wbt;    args[11] = &Wihb;  args[12] = &Whhb;
        args[13] = &cntd;   args[14] = &startd; args[15] = &nextd;
        args[16] = &cntn;   args[17] = &startn; args[18] = &nextn;
        args[19] = &srcn;   args[20] = &dpos;   args[21] = &bondq;
        args[22] = &msg;    // note: order must match signature below
        // signature order: ..., msgb, total, total2, hout
        void* args_full[25];
        for (int i = 0; i < 22; ++i) args_full[i] = args[i];
        args_full[22] = &msg;   // msgb
        args_full[23] = &total; // total
        // rebuild cleanly to avoid confusion:
        void* A[25];
        A[0]=(void*)&atom; A[1]=(void*)&bond; A[2]=(void*)&pair;
        A[3]=(void*)&Wb;   A[4]=(void*)&bb;  A[5]=(void*)&W_ih; A[6]=(void*)&W_hh;
        A[7]=(void*)&b_ih; A[8]=(void*)&b_hh;
        A[9]=&hbf; A[10]=&Wbt; A[11]=&Wihb; A[12]=&Whhb;
        A[13]=&cntd; A[14]=&startd; A[15]=&nextd;
        A[16]=&cntn; A[17]=&startn; A[18]=&nextn;
        A[19]=&srcn; A[20]=&dpos; A[21]=&bondq;
        A[22]=&msg; A[23]=&total;
        void* B[26];
        for (int i = 0; i < 24; ++i) B[i] = A[i];
        B[24] = &total2;
        B[25] = &out;
        // final arg array: 26 entries? signature has 25 params. Count:
        // atom,bond,pair,Wb,bb,Wih,Whh,bih,bhh (9) + hbf,Wbt,Wihb,Whhb (4)
        // + cntd,startd,nextd,cntn,startn,nextn (6) + srcn,dpos,bondq (3)
        // + msgb,total,total2,hout (4) = 26 params.
        void* FA[26];
        FA[0]=(void*)&atom; FA[1]=(void*)&bond; FA[2]=(void*)&pair;
        FA[3]=(void*)&Wb;   FA[4]=(void*)&bb;  FA[5]=(void*)&W_ih; FA[6]=(void*)&W_hh;
        FA[7]=(void*)&b_ih; FA[8]=(void*)&b_hh;
        FA[9]=&hbf; FA[10]=&Wbt; FA[11]=&Wihb; FA[12]=&Whhb;
        FA[13]=&cntd; FA[14]=&startd; FA[15]=&nextd;
        FA[16]=&cntn; FA[17]=&startn; FA[18]=&nextn;
        FA[19]=&srcn; FA[20]=&dpos; FA[21]=&bondq;
        FA[22]=&msg; FA[23]=&total; FA[24]=&total2; FA[25]=&out;
        hipLaunchCooperativeKernel((void*)mega_kernel, dim3(nblk), dim3(256),
                                   FA, 0, stream);
    } else {
        // multi-kernel fallback (same algorithm)
        setup_kernel<<<(SETUP_THREADS + 255) / 256, 256, 0, stream>>>(
            atom, Wb, bb, W_ih, W_hh, hbf, Wbt, Wihb, Whhb, cntd, cntn, total, total2);
        hist_kernel<<<(NE + 255) / 256, 256, 0, stream>>>(pair, cntd, cntn);
        alloc_kernel<<<(NA + 1023) / 1024, 1024, 0, stream>>>(cntd, startd, nextd, total);
        alloc_kernel<<<(NA + 1023) / 1024, 1024, 0, stream>>>(cntn, startn, nextn, total2);
        scatter_kernel<<<(NE + 255) / 256, 256, 0, stream>>>(bond, pair, nextd, nextn,
                                                             srcn, dpos, bondq);
        const int gru_blocks = (ATILES + 3) / 4;
        for (int s = 0; s < STEPS; ++s) {
            msg_kernel<<<512, 256, 0, stream>>>(hbf, bondq, srcn, dpos, Wbt, msg);
            gru_kernel<<<gru_blocks, 256, 0, stream>>>(msg, startd, cntd, hbf,
                                                       Wihb, Whhb, b_ih, b_hh, out,
                                                       (s == STEPS - 1) ? 1 : 0);
        }
    }
}

// Round 19
// 194.654 us; speedup vs baseline: 1.1681x; 1.1681x over previous
//
#include <hip/hip_runtime.h>
#include <hip/hip_cooperative_groups.h>

namespace cg = cooperative_groups;

#define NA 100000
#define NE 300000
#define STEPS 4
#define NTILES (NE / 16)        // 18750 (exact)
#define ATILES (NA / 16)        // 6250  (exact)

typedef _Float16 f16;
typedef _Float16 half8 __attribute__((ext_vector_type(8)));
using f32x4 = __attribute__((ext_vector_type(4))) float;

// ---------------------------------------------------------------------------
// shared phase bodies (identical arithmetic to proven r11/r12/r14 kernels)
// ---------------------------------------------------------------------------
__device__ __forceinline__ void msg_body(
    const f16* __restrict__ h, const f16* __restrict__ bondp,
    const int* __restrict__ nbrp, const f16* __restrict__ Wbt,
    f16* __restrict__ msgb, int wid, int nw, int col, int kg)
{
    half8 w0[17], w1[17];
#pragma unroll
    for (int t = 0; t < 17; ++t) {
        w0[t] = *reinterpret_cast<const half8*>(Wbt + (t * 32 + col) * 32 + kg * 8);
        w1[t] = *reinterpret_cast<const half8*>(Wbt + (t * 32 + 16 + col) * 32 + kg * 8);
    }
    int tile = wid;
    int pos = 0;
    half8 hf{}, cA{}, cB{};
    if (tile < NTILES) {
        pos = tile * 16 + col;
        int nbr0 = nbrp[pos];
        cA = *reinterpret_cast<const half8*>(bondp + (size_t)pos * 16);
        cB = *reinterpret_cast<const half8*>(bondp + (size_t)pos * 16 + 8);
        hf = *reinterpret_cast<const half8*>(h + (size_t)nbr0 * 32 + kg * 8);
    }
    while (tile < NTILES) {
        int tile2 = tile + nw;
        int pos2 = 0;
        half8 hf2{}, cA2{}, cB2{};
        if (tile2 < NTILES) {
            pos2 = tile2 * 16 + col;
            int nbr2 = nbrp[pos2];
            cA2 = *reinterpret_cast<const half8*>(bondp + (size_t)pos2 * 16);
            cB2 = *reinterpret_cast<const half8*>(bondp + (size_t)pos2 * 16 + 8);
            hf2 = *reinterpret_cast<const half8*>(h + (size_t)nbr2 * 32 + kg * 8);
        }
        f32x4 acc0 = {0.f, 0.f, 0.f, 0.f};
        f32x4 acc1 = {0.f, 0.f, 0.f, 0.f};
#pragma unroll
        for (int t = 0; t < 16; ++t) {
            f16 ch = (t < 8) ? cA[t] : cB[t - 8];
            half8 a = hf * ch;               // v_pk_mul_f16 x4
            acc0 = __builtin_amdgcn_mfma_f32_16x16x32_f16(w0[t], a, acc0, 0, 0, 0);
            acc1 = __builtin_amdgcn_mfma_f32_16x16x32_f16(w1[t], a, acc1, 0, 0, 0);
        }
        acc0 = __builtin_amdgcn_mfma_f32_16x16x32_f16(w0[16], hf, acc0, 0, 0, 0);
        acc1 = __builtin_amdgcn_mfma_f32_16x16x32_f16(w1[16], hf, acc1, 0, 0, 0);

        half8 so;   // i = kg*8 .. kg*8+7 (contiguous via Wbt row permute)
        so[0]=(f16)acc0[0]; so[1]=(f16)acc0[1]; so[2]=(f16)acc0[2]; so[3]=(f16)acc0[3];
        so[4]=(f16)acc1[0]; so[5]=(f16)acc1[1]; so[6]=(f16)acc1[2]; so[7]=(f16)acc1[3];
        *reinterpret_cast<half8*>(msgb + (size_t)pos * 32 + kg * 8) = so;

        tile = tile2; pos = pos2; hf = hf2; cA = cA2; cB = cB2;
    }
}

__device__ __forceinline__ void gru_body(
    const f16* __restrict__ msgb, const int* __restrict__ start,
    const int* __restrict__ cnt, f16* __restrict__ h,
    const f16* __restrict__ Wihb, const f16* __restrict__ Whhb,
    const float* __restrict__ bih, const float* __restrict__ bhh,
    float* __restrict__ hout, int wf, int wid, int nw, int col, int kg)
{
    half8 wi[6], wh[6];
#pragma unroll
    for (int t = 0; t < 6; ++t) {
        wi[t] = *reinterpret_cast<const half8*>(Wihb + (size_t)(t * 16 + col) * 32 + kg * 8);
        wh[t] = *reinterpret_cast<const half8*>(Whhb + (size_t)(t * 16 + col) * 32 + kg * 8);
    }
    float br0  = bih[col]      + bhh[col];
    float bz0  = bih[32 + col] + bhh[32 + col];
    float bin0 = bih[64 + col];
    float bhn0 = bhh[64 + col];
    float br1  = bih[16 + col] + bhh[16 + col];
    float bz1  = bih[48 + col] + bhh[48 + col];
    float bin1 = bih[80 + col];
    float bhn1 = bhh[80 + col];

    for (int tile = wid; tile < ATILES; tile += nw) {
        int base = tile * 16;
        int a0   = base + col;
        int st = start[a0], en = st + cnt[a0];
        half8 hfrag = *reinterpret_cast<const half8*>(h + (size_t)a0 * 32 + kg * 8);

        float xs[8] = {0.f, 0.f, 0.f, 0.f, 0.f, 0.f, 0.f, 0.f};
        int p = st;
        while (p < en) {
            int n = en - p;
            half8 m0, m1, m2, m3;
            m0 = *reinterpret_cast<const half8*>(msgb + (size_t)p * 32 + kg * 8);
            if (n > 1) m1 = *reinterpret_cast<const half8*>(msgb + (size_t)(p + 1) * 32 + kg * 8);
            if (n > 2) m2 = *reinterpret_cast<const half8*>(msgb + (size_t)(p + 2) * 32 + kg * 8);
            if (n > 3) m3 = *reinterpret_cast<const half8*>(msgb + (size_t)(p + 3) * 32 + kg * 8);
#pragma unroll
            for (int j = 0; j < 8; ++j) xs[j] += (float)m0[j];
            if (n > 1) {
#pragma unroll
                for (int j = 0; j < 8; ++j) xs[j] += (float)m1[j];
            }
            if (n > 2) {
#pragma unroll
                for (int j = 0; j < 8; ++j) xs[j] += (float)m2[j];
            }
            if (n > 3) {
#pragma unroll
                for (int j = 0; j < 8; ++j) xs[j] += (float)m3[j];
            }
            p += 4;
        }
        half8 xfrag;
#pragma unroll
        for (int j = 0; j < 8; ++j) xfrag[j] = (f16)xs[j];

        f32x4 gi[6], gh[6];
#pragma unroll
        for (int t = 0; t < 6; ++t) {
            f32x4 z = {0.f, 0.f, 0.f, 0.f};
            gi[t] = __builtin_amdgcn_mfma_f32_16x16x32_f16(xfrag, wi[t], z, 0, 0, 0);
            gh[t] = __builtin_amdgcn_mfma_f32_16x16x32_f16(hfrag, wh[t], z, 0, 0, 0);
        }

#pragma unroll
        for (int hh = 0; hh < 2; ++hh) {
            float br  = hh ? br1  : br0;
            float bz  = hh ? bz1  : bz0;
            float bin = hh ? bin1 : bin0;
            float bhn = hh ? bhn1 : bhn0;
            int i = hh * 16 + col;
#pragma unroll
            for (int reg = 0; reg < 4; ++reg) {
                int a = base + kg * 4 + reg;
                float r = 1.f / (1.f + __expf(-(gi[hh][reg] + gh[hh][reg] + br)));
                float z = 1.f / (1.f + __expf(-(gi[2 + hh][reg] + gh[2 + hh][reg] + bz)));
                float n = tanhf(gi[4 + hh][reg] + bin + r * (gh[4 + hh][reg] + bhn));
                float hp = (float)h[(size_t)a * 32 + i];
                float o  = (1.f - z) * n + z * hp;
                if (wf) hout[(size_t)a * 32 + i] = o;
                h[(size_t)a * 32 + i] = (f16)o;
            }
        }
    }
}

// ---------------------------------------------------------------------------
// setup body (shared by mega kernel phase 0 and the fallback setup_kernel)
// ---------------------------------------------------------------------------
__device__ __forceinline__ void setup_item(
    int t, const float* __restrict__ atom,
    const float* __restrict__ Wb, const float* __restrict__ bb,
    const float* __restrict__ Wih, const float* __restrict__ Whh,
    f16* __restrict__ hbf, f16* __restrict__ Wbt,
    f16* __restrict__ Wihb, f16* __restrict__ Whhb,
    int* __restrict__ rowcnt, int* __restrict__ total)
{
    const int NH8 = NA * 32 / 8;                 // 400000
    if (t < NH8) {
        float4 a = reinterpret_cast<const float4*>(atom)[2 * t];
        float4 b = reinterpret_cast<const float4*>(atom)[2 * t + 1];
        half8 o;
        o[0]=(f16)a.x; o[1]=(f16)a.y; o[2]=(f16)a.z; o[3]=(f16)a.w;
        o[4]=(f16)b.x; o[5]=(f16)b.y; o[6]=(f16)b.z; o[7]=(f16)b.w;
        reinterpret_cast<half8*>(hbf)[t] = o;
        return;
    }
    int u = t - NH8;
    if (u < NA) {
        rowcnt[u] = 0;
        if (u == 0) *total = 0;
        return;
    }
    int v = u - NA;
    if (v < 17 * 32 * 32) {
        int j = v & 31, i = (v >> 5) & 31, k = v >> 10;
        float val = (k < 16) ? Wb[k * 1024 + i * 32 + j] : bb[i * 32 + j];
        int row = ((i & 4) ? 16 : 0) + ((i >> 3) << 2) + (i & 3);  // i = kg*8.. permute
        Wbt[(k * 32 + row) * 32 + j] = (f16)val;
    } else if (v < 17 * 32 * 32 + 3072) {
        int q = v - 17 * 32 * 32;
        Wihb[q] = (f16)Wih[q];
    } else if (v < 17 * 32 * 32 + 6144) {
        int q = v - 17 * 32 * 32 - 3072;
        Whhb[q] = (f16)Whh[q];
    }
}

__device__ __forceinline__ void scatter_item(
    int e, const float* __restrict__ bond, const int* __restrict__ pair,
    int* __restrict__ next, int* __restrict__ nbrp, f16* __restrict__ bondp)
{
    int2 p = reinterpret_cast<const int2*>(pair)[e];
    int pos = atomicAdd(&next[p.x], 1);
    nbrp[pos] = p.y;
    const float4* b4 = reinterpret_cast<const float4*>(bond + (size_t)e * 16);
    float4 b0 = b4[0], b1 = b4[1], b2 = b4[2], b3 = b4[3];
    half8 o0, o1;
    o0[0]=(f16)b0.x; o0[1]=(f16)b0.y; o0[2]=(f16)b0.z; o0[3]=(f16)b0.w;
    o0[4]=(f16)b1.x; o0[5]=(f16)b1.y; o0[6]=(f16)b1.z; o0[7]=(f16)b1.w;
    o1[0]=(f16)b2.x; o1[1]=(f16)b2.y; o1[2]=(f16)b2.z; o1[3]=(f16)b2.w;
    o1[4]=(f16)b3.x; o1[5]=(f16)b3.y; o1[6]=(f16)b3.z; o1[7]=(f16)b3.w;
    half8* dst = reinterpret_cast<half8*>(bondp + (size_t)pos * 16);
    dst[0] = o0; dst[1] = o1;
}

#define SETUP_THREADS (NA * 32 / 8 + NA + 17 * 32 * 32 + 6144)

// ---------------------------------------------------------------------------
// THE single mega kernel: setup -> hist -> alloc -> scatter -> 4x(msg,gru)
// ---------------------------------------------------------------------------
__global__ __launch_bounds__(256, 2) void mega_kernel(
    const float* __restrict__ atom, const float* __restrict__ bond,
    const int* __restrict__ pair,
    const float* __restrict__ Wb, const float* __restrict__ bb,
    const float* __restrict__ Wih, const float* __restrict__ Whh,
    const float* __restrict__ bih, const float* __restrict__ bhh,
    f16* __restrict__ hbf, f16* __restrict__ Wbt,
    f16* __restrict__ Wihb, f16* __restrict__ Whhb,
    int* __restrict__ rowcnt, int* __restrict__ startp, int* __restrict__ nextp,
    int* __restrict__ nbrp, f16* __restrict__ bondp,
    f16* __restrict__ msgb, int* __restrict__ total,
    float* __restrict__ hout)
{
    __shared__ int scan[256];
    __shared__ int sbase;

    cg::grid_group grid = cg::this_grid();
    int gtid = blockIdx.x * 256 + threadIdx.x;
    int gsz  = gridDim.x * 256;

    // phase 0: converts + zeroing + weight prep
    for (int t = gtid; t < SETUP_THREADS; t += gsz)
        setup_item(t, atom, Wb, bb, Wih, Whh, hbf, Wbt, Wihb, Whhb, rowcnt, total);
    grid.sync();

    // phase 1: degree histogram
    for (int e = gtid; e < NE; e += gsz)
        atomicAdd(&rowcnt[reinterpret_cast<const int2*>(pair)[e].x], 1);
    grid.sync();

    // phase 2: segment allocation (256-chunk LDS scan + atomic base)
    const int NCHUNK = (NA + 255) / 256;
    for (int chunk = blockIdx.x; chunk < NCHUNK; chunk += gridDim.x) {
        int g = chunk * 256 + threadIdx.x;
        int v = (g < NA) ? rowcnt[g] : 0;
        scan[threadIdx.x] = v;
        __syncthreads();
        for (int off = 1; off < 256; off <<= 1) {
            int u = (threadIdx.x >= off) ? scan[threadIdx.x - off] : 0;
            __syncthreads();
            scan[threadIdx.x] += u;
            __syncthreads();
        }
        if (threadIdx.x == 255) sbase = atomicAdd(total, scan[255]);
        __syncthreads();
        if (g < NA) {
            int s = sbase + scan[threadIdx.x] - v;
            startp[g] = s;
            nextp[g]  = s;
        }
        __syncthreads();
    }
    grid.sync();

    // phase 3: scatter (nbr + bond fp16, dst-sorted)
    for (int e = gtid; e < NE; e += gsz)
        scatter_item(e, bond, pair, nextp, nbrp, bondp);
    grid.sync();

    // phase 4: the 4-step loop (proven r14 bodies)
    int wave = threadIdx.x >> 6;
    int lane = threadIdx.x & 63;
    int col  = lane & 15;
    int kg   = lane >> 4;
    int wid  = blockIdx.x * 4 + wave;
    int nw   = gridDim.x << 2;

    for (int s = 0; s < STEPS; ++s) {
        msg_body(hbf, bondp, nbrp, Wbt, msgb, wid, nw, col, kg);
        grid.sync();
        gru_body(msgb, startp, rowcnt, hbf, Wihb, Whhb, bih, bhh, hout,
                 (s == STEPS - 1) ? 1 : 0, wid, nw, col, kg);
        grid.sync();
    }
}

// ---------------------------------------------------------------------------
// fallback path kernels (proven r12/r16 structure)
// ---------------------------------------------------------------------------
__global__ __launch_bounds__(256) void setup_kernel(
    const float* __restrict__ atom,
    const float* __restrict__ Wb, const float* __restrict__ bb,
    const float* __restrict__ Wih, const float* __restrict__ Whh,
    f16* __restrict__ hbf, f16* __restrict__ Wbt,
    f16* __restrict__ Wihb, f16* __restrict__ Whhb,
    int* __restrict__ rowcnt, int* __restrict__ total)
{
    int t = blockIdx.x * 256 + threadIdx.x;
    if (t < SETUP_THREADS)
        setup_item(t, atom, Wb, bb, Wih, Whh, hbf, Wbt, Wihb, Whhb, rowcnt, total);
}

__global__ __launch_bounds__(256) void hist_kernel(
    const int* __restrict__ pair, int* __restrict__ cnt)
{
    int e = blockIdx.x * 256 + threadIdx.x;
    if (e < NE) atomicAdd(&cnt[reinterpret_cast<const int2*>(pair)[e].x], 1);
}

__global__ __launch_bounds__(1024) void alloc_kernel(
    const int* __restrict__ cnt, int* __restrict__ start,
    int* __restrict__ next, int* __restrict__ total)
{
    __shared__ int tmp[1024];
    __shared__ int base;
    int g = blockIdx.x * 1024 + threadIdx.x;
    int v = (g < NA) ? cnt[g] : 0;
    tmp[threadIdx.x] = v;
    __syncthreads();
    for (int off = 1; off < 1024; off <<= 1) {
        int u = (threadIdx.x >= off) ? tmp[threadIdx.x - off] : 0;
        __syncthreads();
        tmp[threadIdx.x] += u;
        __syncthreads();
    }
    if (threadIdx.x == 1023) base = atomicAdd(total, tmp[1023]);
    __syncthreads();
    if (g < NA) {
        int s = base + tmp[threadIdx.x] - v;
        start[g] = s;
        next[g] = s;
    }
}

__global__ __launch_bounds__(256) void scatter_kernel(
    const float* __restrict__ bond, const int* __restrict__ pair,
    int* __restrict__ next, int* __restrict__ nbrp, f16* __restrict__ bondp)
{
    int e = blockIdx.x * 256 + threadIdx.x;
    if (e < NE) scatter_item(e, bond, pair, next, nbrp, bondp);
}

__global__ __launch_bounds__(256, 2) void msg_kernel(
    const f16* __restrict__ hb, const f16* __restrict__ bondp,
    const int* __restrict__ nbrp, const f16* __restrict__ Wbt,
    f16* __restrict__ msgb)
{
    int wave = threadIdx.x >> 6;
    int lane = threadIdx.x & 63;
    msg_body(hb, bondp, nbrp, Wbt, msgb,
             blockIdx.x * 4 + wave, gridDim.x << 2, lane & 15, lane >> 4);
}

__global__ __launch_bounds__(256) void gru_kernel(
    const f16* __restrict__ msgb, const int* __restrict__ start,
    const int* __restrict__ cnt, f16* __restrict__ hb,
    const f16* __restrict__ Wihb, const f16* __restrict__ Whhb,
    const float* __restrict__ bih, const float* __restrict__ bhh,
    float* __restrict__ hout, int wf)
{
    int wave = threadIdx.x >> 6;
    int lane = threadIdx.x & 63;
    gru_body(msgb, start, cnt, hb, Wihb, Whhb, bih, bhh, hout, wf,
             blockIdx.x * 4 + wave, gridDim.x << 2, lane & 15, lane >> 4);
}

extern "C" void kernel_launch(void* const* d_in, const int* in_sizes, int n_in,
                              void* d_out, int out_size, void* d_ws, size_t ws_size,
                              hipStream_t stream)
{
    const float* atom = (const float*)d_in[0];
    const float* bond = (const float*)d_in[1];
    const int*   pair = (const int*)  d_in[2];
    const float* Wb   = (const float*)d_in[3];
    const float* bb   = (const float*)d_in[4];
    const float* W_ih = (const float*)d_in[5];
    const float* W_hh = (const float*)d_in[6];
    const float* b_ih = (const float*)d_in[7];
    const float* b_hh = (const float*)d_in[8];
    float* out = (float*)d_out;

    char* w = (char*)d_ws;
    f16* msg    = (f16*)w;                       // 19,200,000 B
    f16* hbf    = (f16*)(w + 19200000);          //  6,400,000
    f16* bondp  = (f16*)(w + 25600000);          //  9,600,000
    f16* Wbt    = (f16*)(w + 35200000);          //     34,816
    f16* Wihb   = Wbt + 17 * 32 * 32;            //      6,144
    f16* Whhb   = Wihb + 96 * 32;                //      6,144
    int* rowcnt = (int*)(w + 35248000);          //    400,000
    int* startp = (int*)(w + 35648000);          //    400,000
    int* nextp  = (int*)(w + 36048000);          //    400,000
    int* nbrp   = (int*)(w + 36448000);          //  1,200,000
    int* total  = (int*)(w + 37648000);          //          4

    int bpc = 0;
    hipError_t qe = hipOccupancyMaxActiveBlocksPerMultiprocessor(
        &bpc, (const void*)mega_kernel, 256, 0);
    if (qe == hipSuccess && bpc >= 2) {
        int nblk = bpc * 256;
        if (nblk > 2048) nblk = 2048;
        void* args[21];
        args[0]  = (void*)&atom;  args[1]  = (void*)&bond;  args[2]  = (void*)&pair;
        args[3]  = (void*)&Wb;    args[4]  = (void*)&bb;
        args[5]  = (void*)&W_ih;  args[6]  = (void*)&W_hh;
        args[7]  = (void*)&b_ih;  args[8]  = (void*)&b_hh;
        args[9]  = &hbf;   args[10] = &Wbt;   args[11] = &Wihb;  args[12] = &Whhb;
        args[13] = &rowcnt; args[14] = &startp; args[15] = &nextp;
        args[16] = &nbrp;  args[17] = &bondp; args[18] = &msg;
        args[19] = &total; args[20] = &out;
        hipLaunchCooperativeKernel((void*)mega_kernel, dim3(nblk), dim3(256),
                                   args, 0, stream);
    } else {
        // proven multi-kernel fallback
        setup_kernel<<<(SETUP_THREADS + 255) / 256, 256, 0, stream>>>(
            atom, Wb, bb, W_ih, W_hh, hbf, Wbt, Wihb, Whhb, rowcnt, total);
        hist_kernel<<<(NE + 255) / 256, 256, 0, stream>>>(pair, rowcnt);
        alloc_kernel<<<(NA + 1023) / 1024, 1024, 0, stream>>>(rowcnt, startp, nextp, total);
        scatter_kernel<<<(NE + 255) / 256, 256, 0, stream>>>(bond, pair, nextp, nbrp, bondp);
        const int gru_blocks = (ATILES + 3) / 4;
        for (int s = 0; s < STEPS; ++s) {
            msg_kernel<<<512, 256, 0, stream>>>(hbf, bondp, nbrp, Wbt, msg);
            gru_kernel<<<gru_blocks, 256, 0, stream>>>(msg, startp, rowcnt, hbf,
                                                       Wihb, Whhb, b_ih, b_hh, out,
                                                       (s == STEPS - 1) ? 1 : 0);
        }
    }
}